// Round 1
// baseline (641.738 us; speedup 1.0000x reference)
//
#include <hip/hip_runtime.h>
#include <hip/hip_bf16.h>
#include <cstdint>

typedef __bf16 bf16x8 __attribute__((ext_vector_type(8)));
typedef float f32x4 __attribute__((ext_vector_type(4)));

#define DEV static __device__ __forceinline__

constexpr int NB = 8;      // batch
constexpr int NC = 512;    // channels C
constexpr int NS = 16384;  // spatial N = H*W
constexpr int ND = 64;     // d = C/8
constexpr int SK = 32;     // split-K blocks in kernel B
constexpr float FPARAM = 10.0f;
constexpr float FEPS = 1e-6f;

DEV unsigned short f2bf(float f) {
  uint32_t u = __builtin_bit_cast(uint32_t, f);
  u += 0x7fffu + ((u >> 16) & 1u);
  return (unsigned short)(u >> 16);
}
DEV float bf2f(unsigned short h) {
  uint32_t u = ((uint32_t)h) << 16;
  return __builtin_bit_cast(float, u);
}
DEV float fmap(float t) {  // 10*relu(t) + exp(10*min(t,0))
  float p = fmaxf(t, 0.0f);
  float m = fminf(t, 0.0f);
  return FPARAM * p + __expf(FPARAM * m);
}

// ---- LDS tile helpers: tile is [rows][64] bf16, row stride 64 elems,
// ---- XOR-swizzled 8-elem (16B) chunks: chunk_phys = chunk_log ^ (row & 7).
DEV void tile_store4(unsigned short* t, int row, int k, ushort4 v) {  // k % 4 == 0
  int ch = (k >> 3) ^ (row & 7);
  *(ushort4*)(t + row * 64 + ch * 8 + (k & 7)) = v;
}
DEV void tile_store8(unsigned short* t, int row, int k, uint4 v) {  // k % 8 == 0
  int ch = (k >> 3) ^ (row & 7);
  *(uint4*)(t + row * 64 + ch * 8) = v;
}
DEV bf16x8 tile_frag(const unsigned short* t, int row, int k) {  // k % 8 == 0
  int ch = (k >> 3) ^ (row & 7);
  uint4 u = *(const uint4*)(t + row * 64 + ch * 8);
  return __builtin_bit_cast(bf16x8, u);
}
DEV f32x4 mfma16(bf16x8 a, bf16x8 b, f32x4 c) {
  return __builtin_amdgcn_mfma_f32_16x16x32_bf16(a, b, c, 0, 0, 0);
}

// ============================================================================
// Kernel A: Q/K projection + bias + feature map.
//   Qt[b][n][m] = fm(sum_c Wq[m][c] x[b][c][n] + bq[m])   (transposed store)
//   Kp[b][m][n] = fm(sum_c Wk[m][c] x[b][c][n] + bk[m])
// Block tile: M=128 (64 Q rows + 64 K rows) x N=128 n, K-loop over 512 c.
// ============================================================================
__global__ __launch_bounds__(256) void kernelA(
    const float* __restrict__ x, const float* __restrict__ Wq,
    const float* __restrict__ bq, const float* __restrict__ Wk,
    const float* __restrict__ bk, unsigned short* __restrict__ Kp,
    unsigned short* __restrict__ Qt) {
  __shared__ unsigned short sW[128 * 64];  // [m][c] chunk-swizzled
  __shared__ unsigned short sX[128 * 64];  // [n][c] chunk-swizzled (transposed x)
  const int t = threadIdx.x;
  const int lane = t & 63, wave = t >> 6;
  const int wm = wave >> 1, wn = wave & 1;  // 2x2 wave grid, 64x64 each
  const int l15 = lane & 15, q = lane >> 4;
  const int n0 = blockIdx.x * 128;
  const int b = blockIdx.y;
  const float* xb = x + (size_t)b * NC * NS;

  f32x4 acc[4][4];
  const f32x4 zero = {0.f, 0.f, 0.f, 0.f};
  for (int i = 0; i < 4; i++)
    for (int j = 0; j < 4; j++) acc[i][j] = zero;

  const int qq = t & 3, grp = t >> 2;
  const int n4 = (grp & 31) * 4, cb = (grp >> 5) * 4;
  const int shfl_base = (t & 63) & ~3;

  for (int c0 = 0; c0 < NC; c0 += 64) {
    __syncthreads();
    // stage W (128 rows of [Wq;Wk], 64 c each)
    {
      int f4 = t & 15;
      for (int it = 0; it < 8; it++) {
        int row = (t >> 4) + it * 16;
        const float* src = (row < 64) ? (Wq + (size_t)row * NC + c0 + f4 * 4)
                                      : (Wk + (size_t)(row - 64) * NC + c0 + f4 * 4);
        float4 v = *(const float4*)src;
        tile_store4(sW, row, f4 * 4,
                    make_ushort4(f2bf(v.x), f2bf(v.y), f2bf(v.z), f2bf(v.w)));
      }
    }
    // stage x^T via 4x4 shfl lane transpose: [n][c] layout
    for (int it = 0; it < 8; it++) {
      int c_l = cb + qq + it * 8;
      float4 v = *(const float4*)(xb + (size_t)(c0 + c_l) * NS + n0 + n4);
      float vv[4] = {v.x, v.y, v.z, v.w};
      float o[4];
      for (int r = 0; r < 4; r++) {
        int j = (qq + r) & 3;
        float send = vv[(qq - r) & 3];
        o[j] = __shfl(send, shfl_base + j);
      }
      tile_store4(sX, n4 + qq, it * 8 + cb,
                  make_ushort4(f2bf(o[0]), f2bf(o[1]), f2bf(o[2]), f2bf(o[3])));
    }
    __syncthreads();
    for (int kk = 0; kk < 64; kk += 32) {
      int kb = kk + q * 8;
      bf16x8 af[4], bg[4];
      for (int i = 0; i < 4; i++) af[i] = tile_frag(sW, wm * 64 + i * 16 + l15, kb);
      for (int j = 0; j < 4; j++) bg[j] = tile_frag(sX, wn * 64 + j * 16 + l15, kb);
      for (int i = 0; i < 4; i++)
        for (int j = 0; j < 4; j++) acc[i][j] = mfma16(af[i], bg[j], acc[i][j]);
    }
  }

  // epilogue: D layout col=lane&15 (n), row=(lane>>4)*4+r (m)
  if (wm == 0) {  // Q rows -> Qt[b][n][m] (transposed, 4 contiguous m per lane)
    for (int i = 0; i < 4; i++) {
      int mb = i * 16 + q * 4;
      float b0 = bq[mb + 0], b1 = bq[mb + 1], b2 = bq[mb + 2], b3 = bq[mb + 3];
      for (int j = 0; j < 4; j++) {
        int n = n0 + wn * 64 + j * 16 + l15;
        f32x4 v = acc[i][j];
        ushort4 o = make_ushort4(f2bf(fmap(v[0] + b0)), f2bf(fmap(v[1] + b1)),
                                 f2bf(fmap(v[2] + b2)), f2bf(fmap(v[3] + b3)));
        *(ushort4*)(Qt + ((size_t)b * NS + n) * ND + mb) = o;
      }
    }
  } else {  // K rows -> Kp[b][m][n]
    for (int i = 0; i < 4; i++) {
      int mb = i * 16 + q * 4;
      float b0 = bk[mb + 0], b1 = bk[mb + 1], b2 = bk[mb + 2], b3 = bk[mb + 3];
      for (int j = 0; j < 4; j++) {
        int n = n0 + wn * 64 + j * 16 + l15;
        f32x4 v = acc[i][j];
        Kp[((size_t)b * ND + mb + 0) * NS + n] = f2bf(fmap(v[0] + b0));
        Kp[((size_t)b * ND + mb + 1) * NS + n] = f2bf(fmap(v[1] + b1));
        Kp[((size_t)b * ND + mb + 2) * NS + n] = f2bf(fmap(v[2] + b2));
        Kp[((size_t)b * ND + mb + 3) * NS + n] = f2bf(fmap(v[3] + b3));
      }
    }
  }
}

// ============================================================================
// Kernel B: split-K partials of KXt[m][c'] = sum_n K'[m][n] * x[c'][n],
// plus Ksum partials. Block: [64 m x 256 c'], K-chunk = 512 n.
// Grid: (SK, 2 c'-halves, B).
// ============================================================================
__global__ __launch_bounds__(256) void kernelB(
    const float* __restrict__ x, const unsigned short* __restrict__ Kp,
    float* __restrict__ Pp, float* __restrict__ KsP) {
  __shared__ unsigned short sK[64 * 64];
  __shared__ unsigned short sX[256 * 64];
  __shared__ float sSum[64];
  const int t = threadIdx.x;
  const int lane = t & 63, wave = t >> 6;
  const int l15 = lane & 15, q = lane >> 4;
  const int s = blockIdx.x, half = blockIdx.y, b = blockIdx.z;
  const int cp0 = half * 256;
  const int nbase = s * (NS / SK);
  if (t < 64) sSum[t] = 0.0f;

  f32x4 acc[4][4];
  const f32x4 zero = {0.f, 0.f, 0.f, 0.f};
  for (int i = 0; i < 4; i++)
    for (int j = 0; j < 4; j++) acc[i][j] = zero;

  for (int nc = 0; nc < NS / SK; nc += 64) {
    int n0 = nbase + nc;
    __syncthreads();
    // stage K' [64 m][64 n]
    for (int it = 0; it < 2; it++) {
      int row = (t >> 3) + it * 32;
      int ch = t & 7;
      uint4 v = *(const uint4*)(Kp + ((size_t)b * ND + row) * NS + n0 + ch * 8);
      tile_store8(sK, row, ch * 8, v);
      if (half == 0) {
        const unsigned short* pv = (const unsigned short*)&v;
        float ssum = 0.f;
        for (int e = 0; e < 8; e++) ssum += bf2f(pv[e]);
        atomicAdd(&sSum[row], ssum);
      }
    }
    // stage x [256 c'][64 n]
    {
      int f4 = t & 15;
      for (int it = 0; it < 16; it++) {
        int row = (t >> 4) + it * 16;
        float4 v = *(const float4*)(x + ((size_t)b * NC + cp0 + row) * NS + n0 + f4 * 4);
        tile_store4(sX, row, f4 * 4,
                    make_ushort4(f2bf(v.x), f2bf(v.y), f2bf(v.z), f2bf(v.w)));
      }
    }
    __syncthreads();
    for (int kk = 0; kk < 64; kk += 32) {
      int kb = kk + q * 8;
      bf16x8 af[4], bg[4];
      for (int i = 0; i < 4; i++) af[i] = tile_frag(sK, i * 16 + l15, kb);
      for (int j = 0; j < 4; j++) bg[j] = tile_frag(sX, wave * 64 + j * 16 + l15, kb);
      for (int i = 0; i < 4; i++)
        for (int j = 0; j < 4; j++) acc[i][j] = mfma16(af[i], bg[j], acc[i][j]);
    }
  }
  // write partials P[b][s][m][c']
  for (int i = 0; i < 4; i++) {
    int mb = i * 16 + q * 4;
    for (int j = 0; j < 4; j++) {
      int cp = cp0 + wave * 64 + j * 16 + l15;
      f32x4 v = acc[i][j];
      for (int r = 0; r < 4; r++)
        Pp[(((size_t)b * SK + s) * ND + mb + r) * NC + cp] = v[r];
    }
  }
  __syncthreads();
  if (half == 0 && t < 64) KsP[((size_t)b * SK + s) * ND + t] = sSum[t];
}

// ============================================================================
// Kernel C1: reduce split-K partials -> KXt[b][m][c'], Ksum[b][m]
// ============================================================================
__global__ __launch_bounds__(256) void kernelC1(
    const float* __restrict__ Pp, const float* __restrict__ KsP,
    float* __restrict__ KXt, float* __restrict__ Ksum) {
  const int m = blockIdx.x, b = blockIdx.y, t = threadIdx.x;
  float a0 = 0.f, a1 = 0.f;
  for (int s = 0; s < SK; s++) {
    const float* p = Pp + (((size_t)b * SK + s) * ND + m) * NC;
    a0 += p[t];
    a1 += p[t + 256];
  }
  float* o = KXt + ((size_t)b * ND + m) * NC;
  o[t] = a0;
  o[t + 256] = a1;
  if (t == 0) {
    float ks = 0.f;
    for (int s = 0; s < SK; s++) ks += KsP[((size_t)b * SK + s) * ND + m];
    Ksum[b * ND + m] = ks;
  }
}

// ============================================================================
// Kernel C2: KVT[b][c][m] = sum_c' KXt[m][c'] Wv[c][c'] + Ksum[m]*bv[c]  (bf16)
// One wave per block; block tile [64 c x 64 m], K-loop over 512 c'.
// ============================================================================
__global__ __launch_bounds__(64) void kernelC2(
    const float* __restrict__ KXt, const float* __restrict__ Wv,
    const float* __restrict__ bv, const float* __restrict__ Ksum,
    unsigned short* __restrict__ KVT) {
  __shared__ unsigned short sA[64 * 64];  // Wv rows c
  __shared__ unsigned short sB[64 * 64];  // KXt rows m
  const int t = threadIdx.x;
  const int l15 = t & 15, q = t >> 4;
  const int ct = blockIdx.x, b = blockIdx.y;
  f32x4 acc[4][4];
  const f32x4 zero = {0.f, 0.f, 0.f, 0.f};
  for (int i = 0; i < 4; i++)
    for (int j = 0; j < 4; j++) acc[i][j] = zero;

  for (int c0 = 0; c0 < NC; c0 += 64) {
    __syncthreads();
    int f4 = t & 15;
    for (int it = 0; it < 16; it++) {
      int row = (t >> 4) + it * 4;
      float4 v = *(const float4*)(Wv + ((size_t)(ct * 64 + row)) * NC + c0 + f4 * 4);
      tile_store4(sA, row, f4 * 4,
                  make_ushort4(f2bf(v.x), f2bf(v.y), f2bf(v.z), f2bf(v.w)));
      float4 w = *(const float4*)(KXt + ((size_t)b * ND + row) * NC + c0 + f4 * 4);
      tile_store4(sB, row, f4 * 4,
                  make_ushort4(f2bf(w.x), f2bf(w.y), f2bf(w.z), f2bf(w.w)));
    }
    __syncthreads();
    for (int kk = 0; kk < 64; kk += 32) {
      int kb = kk + q * 8;
      bf16x8 af[4], bg[4];
      for (int i = 0; i < 4; i++) af[i] = tile_frag(sA, i * 16 + l15, kb);
      for (int j = 0; j < 4; j++) bg[j] = tile_frag(sB, j * 16 + l15, kb);
      for (int i = 0; i < 4; i++)
        for (int j = 0; j < 4; j++) acc[i][j] = mfma16(af[i], bg[j], acc[i][j]);
    }
  }
  for (int j = 0; j < 4; j++) {
    int m = j * 16 + l15;
    float ks = Ksum[b * ND + m];
    for (int i = 0; i < 4; i++) {
      for (int r = 0; r < 4; r++) {
        int c = ct * 64 + i * 16 + q * 4 + r;
        float v = acc[i][j][r] + ks * bv[c];
        KVT[((size_t)b * NC + c) * ND + m] = f2bf(v);
      }
    }
  }
}

// ============================================================================
// Kernel D: out[b][c][n] = x + gamma * norm[n] * sum_m KVT[c][m] Qt[n][m]
//   norm[n] = 1 / sum_m Qt[n][m] * (Ksum[m] + EPS)
// Block tile [256 c x 128 n], K=64 (single staging). Grid (N/128, C/256, B).
// ============================================================================
__global__ __launch_bounds__(256) void kernelD(
    const float* __restrict__ x, const unsigned short* __restrict__ Qt,
    const unsigned short* __restrict__ KVT, const float* __restrict__ Ksum,
    const float* __restrict__ gamma, float* __restrict__ out) {
  __shared__ unsigned short sA[256 * 64];  // KVT rows c-local
  __shared__ unsigned short sB[128 * 64];  // Qt rows n-local
  __shared__ float sN[128];
  __shared__ float sKs[64];
  const int t = threadIdx.x;
  const int lane = t & 63, wave = t >> 6;
  const int wm = wave >> 1, wn = wave & 1;  // wave tile 128c x 64n
  const int l15 = lane & 15, q = lane >> 4;
  const int n0 = blockIdx.x * 128;
  const int c0 = blockIdx.y * 256;
  const int b = blockIdx.z;
  if (t < 64) sKs[t] = Ksum[b * ND + t] + FEPS;
  {
    int ch = t & 7;
    for (int it = 0; it < 8; it++) {
      int row = (t >> 3) + it * 32;
      uint4 v = *(const uint4*)(KVT + ((size_t)b * NC + c0 + row) * ND + ch * 8);
      tile_store8(sA, row, ch * 8, v);
    }
    for (int it = 0; it < 4; it++) {
      int row = (t >> 3) + it * 32;
      uint4 v = *(const uint4*)(Qt + ((size_t)b * NS + n0 + row) * ND + ch * 8);
      tile_store8(sB, row, ch * 8, v);
    }
  }
  __syncthreads();
  if (t < 128) {
    float sum = 0.f;
    for (int ch = 0; ch < 8; ch++) {
      const unsigned short* p = sB + t * 64 + ((ch ^ (t & 7)) * 8);
      for (int e = 0; e < 8; e++) sum += bf2f(p[e]) * sKs[ch * 8 + e];
    }
    sN[t] = 1.0f / sum;
  }
  __syncthreads();

  f32x4 acc[8][4];
  const f32x4 zero = {0.f, 0.f, 0.f, 0.f};
  for (int i = 0; i < 8; i++)
    for (int j = 0; j < 4; j++) acc[i][j] = zero;
  for (int kk = 0; kk < 64; kk += 32) {
    int kb = kk + q * 8;
    bf16x8 af[8], bg[4];
    for (int i = 0; i < 8; i++) af[i] = tile_frag(sA, wm * 128 + i * 16 + l15, kb);
    for (int j = 0; j < 4; j++) bg[j] = tile_frag(sB, wn * 64 + j * 16 + l15, kb);
    for (int i = 0; i < 8; i++)
      for (int j = 0; j < 4; j++) acc[i][j] = mfma16(af[i], bg[j], acc[i][j]);
  }
  float g = gamma[0];
  for (int i = 0; i < 8; i++) {
    int cb = c0 + wm * 128 + i * 16 + q * 4;
    for (int j = 0; j < 4; j++) {
      int nl = wn * 64 + j * 16 + l15;
      int n = n0 + nl;
      float nr = sN[nl] * g;
      f32x4 v = acc[i][j];
      for (int r = 0; r < 4; r++) {
        size_t idx = ((size_t)b * NC + cb + r) * NS + n;
        out[idx] = x[idx] + nr * v[r];
      }
    }
  }
}

extern "C" void kernel_launch(void* const* d_in, const int* in_sizes, int n_in,
                              void* d_out, int out_size, void* d_ws, size_t ws_size,
                              hipStream_t stream) {
  (void)in_sizes; (void)n_in; (void)out_size; (void)ws_size;
  const float* x = (const float*)d_in[0];
  const float* Wq = (const float*)d_in[1];
  const float* bq = (const float*)d_in[2];
  const float* Wk = (const float*)d_in[3];
  const float* bk = (const float*)d_in[4];
  const float* Wv = (const float*)d_in[5];
  const float* bv = (const float*)d_in[6];
  const float* gamma = (const float*)d_in[7];
  float* out = (float*)d_out;

  char* ws = (char*)d_ws;
  unsigned short* Qt = (unsigned short*)ws;  ws += (size_t)NB * NS * ND * 2;   // 16.78 MB
  unsigned short* Kp = (unsigned short*)ws;  ws += (size_t)NB * ND * NS * 2;   // 16.78 MB
  float* Pp = (float*)ws;                    ws += (size_t)NB * SK * ND * NC * 4;  // 33.55 MB
  float* KsP = (float*)ws;                   ws += (size_t)NB * SK * ND * 4;   // 64 KB
  float* KXt = (float*)ws;                   ws += (size_t)NB * ND * NC * 4;   // 1 MB
  float* Ksum = (float*)ws;                  ws += (size_t)NB * ND * 4;        // 2 KB
  unsigned short* KVT = (unsigned short*)ws; ws += (size_t)NB * NC * ND * 2;   // 0.5 MB

  kernelA<<<dim3(NS / 128, NB), dim3(256), 0, stream>>>(x, Wq, bq, Wk, bk, Kp, Qt);
  kernelB<<<dim3(SK, 2, NB), dim3(256), 0, stream>>>(x, Kp, Pp, KsP);
  kernelC1<<<dim3(ND, NB), dim3(256), 0, stream>>>(Pp, KsP, KXt, Ksum);
  kernelC2<<<dim3(NC / 64, NB), dim3(64), 0, stream>>>(KXt, Wv, bv, Ksum, KVT);
  kernelD<<<dim3(NS / 128, NC / 256, NB), dim3(256), 0, stream>>>(x, Qt, KVT, Ksum, gamma, out);
}